// Round 9
// baseline (529.141 us; speedup 1.0000x reference)
//
#include <hip/hip_runtime.h>
#include <hip/hip_bf16.h>
#include <stdint.h>

#define AS_G __attribute__((address_space(1)))
#define AS_L __attribute__((address_space(3)))

typedef short bf16x8 __attribute__((ext_vector_type(8)));   // bits of 8 bf16
typedef float f32x4  __attribute__((ext_vector_type(4)));
typedef float f32x16 __attribute__((ext_vector_type(16)));
typedef unsigned int u32x2 __attribute__((ext_vector_type(2)));

// Problem constants (B=32, N=1024, D=512, H=8, DH=64)
constexpr int   M_ROWS = 32768;                    // B*N
constexpr float QSCALE = 0.18033688011112042f;     // log2(e) / sqrt(64)

__device__ __forceinline__ ushort f2bf(float f) {  // hw RTNE f32->bf16
  union { __hip_bfloat16 h; ushort u; } c;
  c.h = __float2bfloat16(f);
  return c.u;
}
__device__ __forceinline__ uint32_t pack2bf(float lo, float hi) {
  union { __hip_bfloat162 b; uint32_t u; } r;
  r.b.x = __float2bfloat16(lo);
  r.b.y = __float2bfloat16(hi);
  return r.u;
}
// permlane32_swap(x,x): returns {dup_lo(x), dup_hi(x)} as an unordered set —
// used ONLY in symmetric reductions (fmax / +), correct under either
// dst/src row-order convention.
__device__ __forceinline__ u32x2 pswap(uint32_t x) {
  return __builtin_amdgcn_permlane32_swap(x, x, false, false);
}
__device__ __forceinline__ void gload16(const ushort* g, ushort* l) {
  // async global->LDS, 16B/lane; LDS dest must be uniform_base + lane*16
  __builtin_amdgcn_global_load_lds((const AS_G uint32_t*)g, (AS_L uint32_t*)l, 16, 0, 0);
}

// ---------------- f32 -> bf16 convert (x + 3 W in one launch) ----------------
__device__ __forceinline__ void cvt8(const float* __restrict__ in,
                                     ushort* __restrict__ out, int i) {
  float4 a = reinterpret_cast<const float4*>(in)[2 * i];
  float4 b = reinterpret_cast<const float4*>(in)[2 * i + 1];
  ushort4 o0 = {f2bf(a.x), f2bf(a.y), f2bf(a.z), f2bf(a.w)};
  ushort4 o1 = {f2bf(b.x), f2bf(b.y), f2bf(b.z), f2bf(b.w)};
  reinterpret_cast<ushort4*>(out)[2 * i]     = o0;
  reinterpret_cast<ushort4*>(out)[2 * i + 1] = o1;
}

__global__ __launch_bounds__(256) void cvt_all_kernel(
    const float* __restrict__ x,  const float* __restrict__ wq,
    const float* __restrict__ wk, const float* __restrict__ wv,
    ushort* __restrict__ xb, ushort* __restrict__ wb) {
  const int b = blockIdx.x, t = threadIdx.x;
  if (b < 2048) {                 // x: 2,097,152 groups = 2048*256*4
    const int i0 = b * 256 + t;
#pragma unroll
    for (int rep = 0; rep < 4; ++rep) cvt8(x, xb, i0 + rep * 524288);
  } else {                        // W: 3 mats x 32768 groups (128 blocks each)
    const int c = b - 2048, m = c >> 7;
    const float* src = (m == 0) ? wq : (m == 1 ? wk : wv);
    cvt8(src, wb + m * 262144, (c & 127) * 256 + t);
  }
}

// ---------------- QKV projection GEMM (known-good) ----------------
// C = X @ W^T + bias -> bf16 plane [32768][512]; Q pre-scaled by QSCALE.
__global__ __launch_bounds__(256) void qkv_gemm_kernel(
    const ushort* __restrict__ Xb, const ushort* __restrict__ Wall,
    const float* __restrict__ bq, const float* __restrict__ bk,
    const float* __restrict__ bv,
    ushort* __restrict__ QKV)
{
  __shared__ ushort As[128 * 64];
  __shared__ ushort Bs[128 * 64];

  const int tile = blockIdx.x;
  const int mt  = tile & 255;
  const int cz  = tile >> 8;     // 0..11
  const int mat = cz >> 2;       // 0:q 1:k 2:v
  const int nt  = cz & 3;

  const ushort* W    = Wall + (size_t)mat * (512 * 512);
  const float*  bias = (mat == 0) ? bq : (mat == 1 ? bk : bv);
  ushort*       Out  = QKV + (size_t)mat * ((size_t)M_ROWS * 512);
  const float   oscale = (mat == 0) ? QSCALE : 1.0f;

  const int m0 = mt * 128, n0 = nt * 128;
  const int t = threadIdx.x, lane = t & 63, wave = t >> 6;
  const int wr = wave >> 1, wc = wave & 1;
  const int l15 = lane & 15, lg = lane >> 4;

  f32x4 acc[4][4];
#pragma unroll
  for (int i = 0; i < 4; i++)
#pragma unroll
    for (int j = 0; j < 4; j++) acc[i][j] = {0.f, 0.f, 0.f, 0.f};

  for (int kt = 0; kt < 8; ++kt) {
    const int k0 = kt * 64;
    __syncthreads();
#pragma unroll
    for (int i = 0; i < 4; ++i) {
      int c = i * 256 + t, row = c >> 3, col8 = (c & 7) * 8;
      gload16(Xb + (size_t)(m0 + row) * 512 + k0 + col8, As + c * 8);
    }
#pragma unroll
    for (int i = 0; i < 4; ++i) {
      int c = i * 256 + t, row = c >> 3, col8 = (c & 7) * 8;
      gload16(W + (size_t)(n0 + row) * 512 + k0 + col8, Bs + c * 8);
    }
    __syncthreads();
#pragma unroll
    for (int ks = 0; ks < 2; ++ks) {
      bf16x8 af[4], bfr[4];
#pragma unroll
      for (int i = 0; i < 4; ++i) {
        af[i]  = *(const bf16x8*)(As + (wr * 64 + i * 16 + l15) * 64 + ks * 32 + lg * 8);
        bfr[i] = *(const bf16x8*)(Bs + (wc * 64 + i * 16 + l15) * 64 + ks * 32 + lg * 8);
      }
#pragma unroll
      for (int i = 0; i < 4; ++i)
#pragma unroll
        for (int j = 0; j < 4; ++j)
          acc[i][j] = __builtin_amdgcn_mfma_f32_16x16x32_bf16(af[i], bfr[j], acc[i][j], 0, 0, 0);
    }
  }
#pragma unroll
  for (int j = 0; j < 4; ++j) {
    const int col = n0 + wc * 64 + j * 16 + l15;
    const float bc = bias[col];
#pragma unroll
    for (int i = 0; i < 4; ++i) {
      const int row0 = m0 + wr * 64 + i * 16 + lg * 4;
#pragma unroll
      for (int r = 0; r < 4; ++r)
        Out[(size_t)(row0 + r) * 512 + col] = f2bf((acc[i][j][r] + bc) * oscale);
    }
  }
}

// ---------------- V transpose + key permutation --------------------------
// VT'[bh][dh][n64*64 + p] = flatV[bh*65536 + (n64*64 + pi(p))*64 + dh]
// pi(p): with p = tt*32 + s*16 + h*8 + j  ->  tt*32 + 16s + 4h + (j&3) + 8*(j>>2).
// This matches the MFMA C-layout crow() of the swapped QK^T, so the attention
// PV B-fragment needs NO cross-lane exchange.
__global__ __launch_bounds__(256) void vtrans_kernel(
    const ushort* __restrict__ Vn, ushort* __restrict__ VT)
{
  __shared__ ushort T[64][258];   // [dh][n-local], padded stride
  const int bh = blockIdx.x >> 2, nc = blockIdx.x & 3;
  const ushort* src = Vn + (size_t)bh * 65536 + nc * 16384;
  ushort* dst = VT + (size_t)bh * 65536 + nc * 256;
  const int t = threadIdx.x;
#pragma unroll
  for (int i = 0; i < 8; ++i) {   // load [256 n][64 dh], scatter-transpose
    int c = i * 256 + t, n = c >> 3, col8 = (c & 7) * 8;
    ushort tmp[8];
    *(int4*)tmp = *(const int4*)(src + n * 64 + col8);
#pragma unroll
    for (int j = 0; j < 8; ++j) T[col8 + j][n] = tmp[j];
  }
  __syncthreads();
#pragma unroll
  for (int i = 0; i < 8; ++i) {   // write [64 dh][256 n] coalesced, pi-gathered
    int c = i * 256 + t, dh = c >> 5, a8 = (c & 31) * 8;
    const int w = a8 & 63;        // position of this 8-group within its 64-tile
    const int pbase = (a8 & 192) + (w >> 5) * 32 + ((w >> 4) & 1) * 16
                    + ((w >> 3) & 1) * 4;
    ushort tmp[8];
    *(uint64_t*)(tmp)     = *(const uint64_t*)(&T[dh][pbase]);      // j=0..3
    *(uint64_t*)(tmp + 4) = *(const uint64_t*)(&T[dh][pbase + 8]);  // j=4..7
    *(int4*)(dst + (size_t)dh * 1024 + a8) = *(const int4*)tmp;
  }
}

// ---------------- flash attention: 4 waves x 32 q-rows, KVBLK=64, 32x32x16 ----
// Swapped QK^T (S^T = K Q^T) -> lane-local softmax; V key-permuted so the PV
// B-fragment is the lane's own packed P values (no cross-lane exchange).
// K double-buffered in LDS (16 KB); V read DIRECTLY from global (L2-resident
// after the XCD swizzle — m169 precedent: don't stage what L2-fits).
// LDS block 16.5 KB -> up to 8 blocks/CU (was 4 at 33 KB).
__global__ __launch_bounds__(256, 6) void attn_kernel(
    const ushort* __restrict__ QKV,   // planes: Q[bh][n][64], K[bh][n][64]
    const ushort* __restrict__ VTg_,  // V^T [bh][64 dh][1024 n], key-permuted
    float* __restrict__ Out)          // [bh][1024][64] f32
{
  constexpr int PLANE = M_ROWS * 512;
  __shared__ float Lbuf[32 * 129];           // 16512 B
  ushort* sK = (ushort*)Lbuf;                 // [2][4096] = 16384 B (fits)

  const int raw = blockIdx.x;                 // 2048 = 8 XCD chunks x 256
  const int blk = ((raw & 7) << 8) | (raw >> 3);
  const int bh = blk >> 3, qb = blk & 7;
  const ushort* Qg  = QKV + (size_t)bh * 65536;
  const ushort* Kg  = QKV + (size_t)PLANE + (size_t)bh * 65536;
  const ushort* Vtg = VTg_ + (size_t)bh * 65536;

  const int t = threadIdx.x, lane = t & 63, wave = t >> 6;
  const int l31 = lane & 31, h = lane >> 5;
  const int q = qb * 128 + wave * 32 + l31;

  bf16x8 qf[4];
#pragma unroll
  for (int ks = 0; ks < 4; ++ks)
    qf[ks] = *(const bf16x8*)(Qg + (size_t)q * 64 + ks * 16 + h * 8);

  float mrow = -1e30f, lrow = 0.f;
  f32x16 o[2];
#pragma unroll
  for (int r = 0; r < 16; ++r) { o[0][r] = 0.f; o[1][r] = 0.f; }

  // prologue: stage K tile 0
#pragma unroll
  for (int i = 0; i < 2; ++i) {
    int c = i * 256 + t, row = c >> 3, slot = c & 7;
    gload16(Kg + (size_t)row * 64 + ((slot ^ (row & 7)) << 3), sK + c * 8);
  }
  __syncthreads();

  for (int kv = 0; kv < 16; ++kv) {
    const int cur = kv & 1;
    if (kv < 15) {
      const int nx = cur ^ 1, kn = kv + 1;
#pragma unroll
      for (int i = 0; i < 2; ++i) {
        int c = i * 256 + t, row = c >> 3, slot = c & 7;
        gload16(Kg + (size_t)(kn * 64 + row) * 64 + ((slot ^ (row & 7)) << 3),
                sK + nx * 4096 + c * 8);
      }
    }
    const ushort* Kc  = sK + cur * 4096;
    const ushort* Vkv = Vtg + kv * 64;   // V tile base in global (key-permuted)

    // S^T = K Q^T : lane holds S[k = tt*32 + (r&3)+8*(r>>2)+4h][q = l31]
    f32x16 st[2];
#pragma unroll
    for (int tt = 0; tt < 2; ++tt) {
      f32x16 a;
#pragma unroll
      for (int r = 0; r < 16; ++r) a[r] = 0.f;
      __builtin_amdgcn_s_setprio(1);
#pragma unroll
      for (int ks = 0; ks < 4; ++ks) {
        const int krow = tt * 32 + l31;
        bf16x8 kf = *(const bf16x8*)(Kc + krow * 64 + (((ks * 2 + h) ^ (krow & 7)) << 3));
        a = __builtin_amdgcn_mfma_f32_32x32x16_bf16(kf, qf[ks], a, 0, 0, 0);
      }
      __builtin_amdgcn_s_setprio(0);
      st[tt] = a;
    }

    // online softmax (row = q = l31): tree max, cross-half via permlane (symmetric)
    float mx;
    {
      float t8[8];
#pragma unroll
      for (int i = 0; i < 8; ++i)
        t8[i] = fmaxf(fmaxf(st[0][i], st[0][i + 8]), fmaxf(st[1][i], st[1][i + 8]));
      float a0 = fmaxf(fmaxf(t8[0], t8[1]), fmaxf(t8[2], t8[3]));
      float a1 = fmaxf(fmaxf(t8[4], t8[5]), fmaxf(t8[6], t8[7]));
      mx = fmaxf(a0, a1);
    }
    {
      u32x2 d = pswap(__float_as_uint(mx));
      mx = fmaxf(__uint_as_float(d.x), __uint_as_float(d.y));
    }
    if (!__all(mx - mrow <= 8.0f)) {       // defer-max: rescale rare after t0
      const float mnew = fmaxf(mrow, mx);
      const float alpha = exp2f(mrow - mnew);
      mrow = mnew;
      lrow *= alpha;
#pragma unroll
      for (int r = 0; r < 16; ++r) { o[0][r] *= alpha; o[1][r] *= alpha; }
    }
#pragma unroll
    for (int tt = 0; tt < 2; ++tt)
#pragma unroll
      for (int r = 0; r < 16; ++r) st[tt][r] = exp2f(st[tt][r] - mrow);
    {
      float s8[8];
#pragma unroll
      for (int i = 0; i < 8; ++i)
        s8[i] = (st[0][i] + st[0][i + 8]) + (st[1][i] + st[1][i + 8]);
      float rs = ((s8[0] + s8[1]) + (s8[2] + s8[3]))
               + ((s8[4] + s8[5]) + (s8[6] + s8[7]));
      u32x2 d = pswap(__float_as_uint(rs));
      lrow += __uint_as_float(d.x) + __uint_as_float(d.y);
    }

    // O^T += V'^T P'^T : V key-permuted so pf = own packed st values;
    // vf loaded straight from global (L2) — no LDS staging, no shuffle.
#pragma unroll
    for (int tt = 0; tt < 2; ++tt) {
#pragma unroll
      for (int s = 0; s < 2; ++s) {
        union { uint32_t u[4]; bf16x8 v; } pf;
#pragma unroll
        for (int i = 0; i < 4; ++i)
          pf.u[i] = pack2bf(st[tt][8 * s + 2 * i], st[tt][8 * s + 2 * i + 1]);
        const int ks2 = tt * 2 + s;
        __builtin_amdgcn_s_setprio(1);
#pragma unroll
        for (int dt = 0; dt < 2; ++dt) {
          const int drow = dt * 32 + l31;
          bf16x8 vf = *(const bf16x8*)(Vkv + (size_t)drow * 1024 + ks2 * 16 + h * 8);
          o[dt] = __builtin_amdgcn_mfma_f32_32x32x16_bf16(vf, pf.v, o[dt], 0, 0, 0);
        }
        __builtin_amdgcn_s_setprio(0);
      }
    }
    __syncthreads();
  }

  // epilogue: two passes (d-halves) through Lbuf[32][129] -> coalesced stores
  const float linv = 1.f / lrow;
#pragma unroll
  for (int half = 0; half < 2; ++half) {
    __syncthreads();
#pragma unroll
    for (int r = 0; r < 16; ++r) {
      const int dloc = (r & 3) + 8 * (r >> 2) + 4 * h;   // 0..31
      Lbuf[dloc * 129 + wave * 32 + l31] = o[half][r] * linv;
    }
    __syncthreads();
    const int qloc = t >> 1, ds0 = (t & 1) * 16;
    float* ob = Out + (size_t)bh * 65536 + (size_t)(qb * 128 + qloc) * 64
              + half * 32 + ds0;
#pragma unroll
    for (int c = 0; c < 4; ++c) {
      float4 v = { Lbuf[(ds0 + 4 * c + 0) * 129 + qloc],
                   Lbuf[(ds0 + 4 * c + 1) * 129 + qloc],
                   Lbuf[(ds0 + 4 * c + 2) * 129 + qloc],
                   Lbuf[(ds0 + 4 * c + 3) * 129 + qloc] };
      *(float4*)(ob + 4 * c) = v;
    }
  }
}

// ---------------- launch ----------------
extern "C" void kernel_launch(void* const* d_in, const int* in_sizes, int n_in,
                              void* d_out, int out_size, void* d_ws, size_t ws_size,
                              hipStream_t stream) {
  (void)in_sizes; (void)n_in; (void)out_size; (void)ws_size;
  const float* x  = (const float*)d_in[0];
  const float* Wq = (const float*)d_in[1];
  const float* bq = (const float*)d_in[2];
  const float* Wk = (const float*)d_in[3];
  const float* bk = (const float*)d_in[4];
  const float* Wv = (const float*)d_in[5];
  const float* bv = (const float*)d_in[6];

  // ws layout (bytes): Xb/VT[32M] | Wb[1.5M] | QKV[96M]
  // Xb is dead after the GEMM; VT reuses its region.
  ushort* Xb  = (ushort*)d_ws;
  ushort* VT  = (ushort*)d_ws;
  ushort* Wb  = (ushort*)((char*)d_ws + 33554432);
  ushort* QKV = (ushort*)((char*)d_ws + 35127296);
  ushort* Vn  = QKV + 2 * (size_t)M_ROWS * 512;   // natural V plane

  cvt_all_kernel<<<2432, 256, 0, stream>>>(x, Wq, Wk, Wv, Xb, Wb);

  qkv_gemm_kernel<<<256 * 12, 256, 0, stream>>>(Xb, Wb, bq, bk, bv, QKV);

  vtrans_kernel<<<1024, 256, 0, stream>>>(Vn, VT);

  attn_kernel<<<256 * 8, 256, 0, stream>>>(QKV, VT, (float*)d_out);
}

// Round 10
// 518.181 us; speedup vs baseline: 1.0212x; 1.0212x over previous
//
#include <hip/hip_runtime.h>
#include <hip/hip_bf16.h>
#include <stdint.h>

#define AS_G __attribute__((address_space(1)))
#define AS_L __attribute__((address_space(3)))

typedef short bf16x8 __attribute__((ext_vector_type(8)));   // bits of 8 bf16
typedef float f32x4  __attribute__((ext_vector_type(4)));
typedef float f32x16 __attribute__((ext_vector_type(16)));
typedef unsigned int u32x2 __attribute__((ext_vector_type(2)));

// Problem constants (B=32, N=1024, D=512, H=8, DH=64)
constexpr int   M_ROWS = 32768;                    // B*N
constexpr float QSCALE = 0.18033688011112042f;     // log2(e) / sqrt(64)

__device__ __forceinline__ ushort f2bf(float f) {  // hw RTNE f32->bf16
  union { __hip_bfloat16 h; ushort u; } c;
  c.h = __float2bfloat16(f);
  return c.u;
}
__device__ __forceinline__ uint32_t pack2bf(float lo, float hi) {
  union { __hip_bfloat162 b; uint32_t u; } r;
  r.b.x = __float2bfloat16(lo);
  r.b.y = __float2bfloat16(hi);
  return r.u;
}
// permlane32_swap(x,x): returns {dup_lo(x), dup_hi(x)} as an unordered set —
// used ONLY in symmetric reductions (fmax / +), correct under either
// dst/src row-order convention.
__device__ __forceinline__ u32x2 pswap(uint32_t x) {
  return __builtin_amdgcn_permlane32_swap(x, x, false, false);
}
__device__ __forceinline__ void gload16(const ushort* g, ushort* l) {
  // async global->LDS, 16B/lane; LDS dest must be uniform_base + lane*16
  __builtin_amdgcn_global_load_lds((const AS_G uint32_t*)g, (AS_L uint32_t*)l, 16, 0, 0);
}

// ---------------- f32 -> bf16 convert (x + 3 W in one launch) ----------------
__device__ __forceinline__ void cvt8(const float* __restrict__ in,
                                     ushort* __restrict__ out, int i) {
  float4 a = reinterpret_cast<const float4*>(in)[2 * i];
  float4 b = reinterpret_cast<const float4*>(in)[2 * i + 1];
  ushort4 o0 = {f2bf(a.x), f2bf(a.y), f2bf(a.z), f2bf(a.w)};
  ushort4 o1 = {f2bf(b.x), f2bf(b.y), f2bf(b.z), f2bf(b.w)};
  reinterpret_cast<ushort4*>(out)[2 * i]     = o0;
  reinterpret_cast<ushort4*>(out)[2 * i + 1] = o1;
}

__global__ __launch_bounds__(256) void cvt_all_kernel(
    const float* __restrict__ x,  const float* __restrict__ wq,
    const float* __restrict__ wk, const float* __restrict__ wv,
    ushort* __restrict__ xb, ushort* __restrict__ wb) {
  const int b = blockIdx.x, t = threadIdx.x;
  if (b < 2048) {                 // x: 2,097,152 groups = 2048*256*4
    const int i0 = b * 256 + t;
#pragma unroll
    for (int rep = 0; rep < 4; ++rep) cvt8(x, xb, i0 + rep * 524288);
  } else {                        // W: 3 mats x 32768 groups (128 blocks each)
    const int c = b - 2048, m = c >> 7;
    const float* src = (m == 0) ? wq : (m == 1 ? wk : wv);
    cvt8(src, wb + m * 262144, (c & 127) * 256 + t);
  }
}

// ---------------- QKV projection GEMM (known-good) ----------------
// C = X @ W^T + bias -> bf16 plane [32768][512]; Q pre-scaled by QSCALE.
__global__ __launch_bounds__(256) void qkv_gemm_kernel(
    const ushort* __restrict__ Xb, const ushort* __restrict__ Wall,
    const float* __restrict__ bq, const float* __restrict__ bk,
    const float* __restrict__ bv,
    ushort* __restrict__ QKV)
{
  __shared__ ushort As[128 * 64];
  __shared__ ushort Bs[128 * 64];

  const int tile = blockIdx.x;
  const int mt  = tile & 255;
  const int cz  = tile >> 8;     // 0..11
  const int mat = cz >> 2;       // 0:q 1:k 2:v
  const int nt  = cz & 3;

  const ushort* W    = Wall + (size_t)mat * (512 * 512);
  const float*  bias = (mat == 0) ? bq : (mat == 1 ? bk : bv);
  ushort*       Out  = QKV + (size_t)mat * ((size_t)M_ROWS * 512);
  const float   oscale = (mat == 0) ? QSCALE : 1.0f;

  const int m0 = mt * 128, n0 = nt * 128;
  const int t = threadIdx.x, lane = t & 63, wave = t >> 6;
  const int wr = wave >> 1, wc = wave & 1;
  const int l15 = lane & 15, lg = lane >> 4;

  f32x4 acc[4][4];
#pragma unroll
  for (int i = 0; i < 4; i++)
#pragma unroll
    for (int j = 0; j < 4; j++) acc[i][j] = {0.f, 0.f, 0.f, 0.f};

  for (int kt = 0; kt < 8; ++kt) {
    const int k0 = kt * 64;
    __syncthreads();
#pragma unroll
    for (int i = 0; i < 4; ++i) {
      int c = i * 256 + t, row = c >> 3, col8 = (c & 7) * 8;
      gload16(Xb + (size_t)(m0 + row) * 512 + k0 + col8, As + c * 8);
    }
#pragma unroll
    for (int i = 0; i < 4; ++i) {
      int c = i * 256 + t, row = c >> 3, col8 = (c & 7) * 8;
      gload16(W + (size_t)(n0 + row) * 512 + k0 + col8, Bs + c * 8);
    }
    __syncthreads();
#pragma unroll
    for (int ks = 0; ks < 2; ++ks) {
      bf16x8 af[4], bfr[4];
#pragma unroll
      for (int i = 0; i < 4; ++i) {
        af[i]  = *(const bf16x8*)(As + (wr * 64 + i * 16 + l15) * 64 + ks * 32 + lg * 8);
        bfr[i] = *(const bf16x8*)(Bs + (wc * 64 + i * 16 + l15) * 64 + ks * 32 + lg * 8);
      }
#pragma unroll
      for (int i = 0; i < 4; ++i)
#pragma unroll
        for (int j = 0; j < 4; ++j)
          acc[i][j] = __builtin_amdgcn_mfma_f32_16x16x32_bf16(af[i], bfr[j], acc[i][j], 0, 0, 0);
    }
  }
#pragma unroll
  for (int j = 0; j < 4; ++j) {
    const int col = n0 + wc * 64 + j * 16 + l15;
    const float bc = bias[col];
#pragma unroll
    for (int i = 0; i < 4; ++i) {
      const int row0 = m0 + wr * 64 + i * 16 + lg * 4;
#pragma unroll
      for (int r = 0; r < 4; ++r)
        Out[(size_t)(row0 + r) * 512 + col] = f2bf((acc[i][j][r] + bc) * oscale);
    }
  }
}

// ---------------- V transpose + key permutation --------------------------
// VT'[bh][dh][n64*64 + p] = flatV[bh*65536 + (n64*64 + pi(p))*64 + dh]
// pi(p): with p = tt*32 + s*16 + h*8 + j  ->  tt*32 + 16s + 4h + (j&3) + 8*(j>>2).
// This matches the MFMA C-layout crow() of the swapped QK^T, so the attention
// PV B-fragment needs NO cross-lane exchange.
__global__ __launch_bounds__(256) void vtrans_kernel(
    const ushort* __restrict__ Vn, ushort* __restrict__ VT)
{
  __shared__ ushort T[64][258];   // [dh][n-local], padded stride
  const int bh = blockIdx.x >> 2, nc = blockIdx.x & 3;
  const ushort* src = Vn + (size_t)bh * 65536 + nc * 16384;
  ushort* dst = VT + (size_t)bh * 65536 + nc * 256;
  const int t = threadIdx.x;
#pragma unroll
  for (int i = 0; i < 8; ++i) {   // load [256 n][64 dh], scatter-transpose
    int c = i * 256 + t, n = c >> 3, col8 = (c & 7) * 8;
    ushort tmp[8];
    *(int4*)tmp = *(const int4*)(src + n * 64 + col8);
#pragma unroll
    for (int j = 0; j < 8; ++j) T[col8 + j][n] = tmp[j];
  }
  __syncthreads();
#pragma unroll
  for (int i = 0; i < 8; ++i) {   // write [64 dh][256 n] coalesced, pi-gathered
    int c = i * 256 + t, dh = c >> 5, a8 = (c & 31) * 8;
    const int w = a8 & 63;        // position of this 8-group within its 64-tile
    const int pbase = (a8 & 192) + (w >> 5) * 32 + ((w >> 4) & 1) * 16
                    + ((w >> 3) & 1) * 4;
    ushort tmp[8];
    *(uint64_t*)(tmp)     = *(const uint64_t*)(&T[dh][pbase]);      // j=0..3
    *(uint64_t*)(tmp + 4) = *(const uint64_t*)(&T[dh][pbase + 8]);  // j=4..7
    *(int4*)(dst + (size_t)dh * 1024 + a8) = *(const int4*)tmp;
  }
}

// ---------------- flash attention: 4 waves x 32 q-rows, KVBLK=64, 32x32x16 ----
// Swapped QK^T (S^T = K Q^T) -> lane-local softmax; V key-permuted so the PV
// B-fragment is the lane's own packed P values (no cross-lane exchange).
// K double-buffered (issue-early, overlaps compute); V SINGLE-buffered,
// issued after the read-completion barrier (drain covered by 6-block TLP).
// LDS block 24 KB -> 6 blocks/CU (round 7 was 33 KB -> 4).
__global__ __launch_bounds__(256, 6) void attn_kernel(
    const ushort* __restrict__ QKV,   // planes: Q[bh][n][64], K[bh][n][64]
    const ushort* __restrict__ VTg_,  // V^T [bh][64 dh][1024 n], key-permuted
    float* __restrict__ Out)          // [bh][1024][64] f32
{
  constexpr int PLANE = M_ROWS * 512;
  __shared__ ushort SMEM[12288];              // 24576 B: sK[2][4096] | sV[4096]
  ushort* sK = SMEM;
  ushort* sV = SMEM + 8192;
  float* Lbuf = (float*)SMEM;                 // epilogue alias [32][129]=16512 B

  const int raw = blockIdx.x;                 // 2048 = 8 XCD chunks x 256
  const int blk = ((raw & 7) << 8) | (raw >> 3);
  const int bh = blk >> 3, qb = blk & 7;
  const ushort* Qg  = QKV + (size_t)bh * 65536;
  const ushort* Kg  = QKV + (size_t)PLANE + (size_t)bh * 65536;
  const ushort* Vtg = VTg_ + (size_t)bh * 65536;

  const int t = threadIdx.x, lane = t & 63, wave = t >> 6;
  const int l31 = lane & 31, h = lane >> 5;
  const int q = qb * 128 + wave * 32 + l31;

  bf16x8 qf[4];
#pragma unroll
  for (int ks = 0; ks < 4; ++ks)
    qf[ks] = *(const bf16x8*)(Qg + (size_t)q * 64 + ks * 16 + h * 8);

  float mrow = -1e30f, lrow = 0.f;
  f32x16 o[2];
#pragma unroll
  for (int r = 0; r < 16; ++r) { o[0][r] = 0.f; o[1][r] = 0.f; }

  // prologue: issue K0 -> sK[0], V0 -> sV (drained at first in-loop barrier)
#pragma unroll
  for (int i = 0; i < 2; ++i) {
    int c = i * 256 + t, row = c >> 3, slot = c & 7;
    gload16(Kg + (size_t)row * 64 + ((slot ^ (row & 7)) << 3), sK + c * 8);
    gload16(Vtg + (size_t)row * 1024 + ((slot ^ (row & 7)) << 3), sV + c * 8);
  }

  for (int kv = 0; kv < 16; ++kv) {
    const int cur = kv & 1;
    __syncthreads();   // drains vmcnt: K[kv] + V[kv] landed; prior reads done
    if (kv < 15) {     // issue-early K prefetch (overlaps this iter's compute)
      const int kn = kv + 1;
#pragma unroll
      for (int i = 0; i < 2; ++i) {
        int c = i * 256 + t, row = c >> 3, slot = c & 7;
        gload16(Kg + (size_t)(kn * 64 + row) * 64 + ((slot ^ (row & 7)) << 3),
                sK + (cur ^ 1) * 4096 + c * 8);
      }
    }
    const ushort* Kc = sK + cur * 4096;

    // S^T = K Q^T : lane holds S[k = tt*32 + (r&3)+8*(r>>2)+4h][q = l31]
    f32x16 st[2];
#pragma unroll
    for (int tt = 0; tt < 2; ++tt) {
      f32x16 a;
#pragma unroll
      for (int r = 0; r < 16; ++r) a[r] = 0.f;
      __builtin_amdgcn_s_setprio(1);
#pragma unroll
      for (int ks = 0; ks < 4; ++ks) {
        const int krow = tt * 32 + l31;
        bf16x8 kf = *(const bf16x8*)(Kc + krow * 64 + (((ks * 2 + h) ^ (krow & 7)) << 3));
        a = __builtin_amdgcn_mfma_f32_32x32x16_bf16(kf, qf[ks], a, 0, 0, 0);
      }
      __builtin_amdgcn_s_setprio(0);
      st[tt] = a;
    }

    // online softmax (row = q = l31): tree max, cross-half via permlane (symmetric)
    float mx;
    {
      float t8[8];
#pragma unroll
      for (int i = 0; i < 8; ++i)
        t8[i] = fmaxf(fmaxf(st[0][i], st[0][i + 8]), fmaxf(st[1][i], st[1][i + 8]));
      float a0 = fmaxf(fmaxf(t8[0], t8[1]), fmaxf(t8[2], t8[3]));
      float a1 = fmaxf(fmaxf(t8[4], t8[5]), fmaxf(t8[6], t8[7]));
      mx = fmaxf(a0, a1);
    }
    {
      u32x2 d = pswap(__float_as_uint(mx));
      mx = fmaxf(__uint_as_float(d.x), __uint_as_float(d.y));
    }
    if (!__all(mx - mrow <= 8.0f)) {       // defer-max: rescale rare after t0
      const float mnew = fmaxf(mrow, mx);
      const float alpha = exp2f(mrow - mnew);
      mrow = mnew;
      lrow *= alpha;
#pragma unroll
      for (int r = 0; r < 16; ++r) { o[0][r] *= alpha; o[1][r] *= alpha; }
    }
#pragma unroll
    for (int tt = 0; tt < 2; ++tt)
#pragma unroll
      for (int r = 0; r < 16; ++r) st[tt][r] = exp2f(st[tt][r] - mrow);
    {
      float s8[8];
#pragma unroll
      for (int i = 0; i < 8; ++i)
        s8[i] = (st[0][i] + st[0][i + 8]) + (st[1][i] + st[1][i + 8]);
      float rs = ((s8[0] + s8[1]) + (s8[2] + s8[3]))
               + ((s8[4] + s8[5]) + (s8[6] + s8[7]));
      u32x2 d = pswap(__float_as_uint(rs));
      lrow += __uint_as_float(d.x) + __uint_as_float(d.y);
    }

    // O^T += V'^T P'^T : V key-permuted so pf = own packed st values.
#pragma unroll
    for (int tt = 0; tt < 2; ++tt) {
#pragma unroll
      for (int s = 0; s < 2; ++s) {
        union { uint32_t u[4]; bf16x8 v; } pf;
#pragma unroll
        for (int i = 0; i < 4; ++i)
          pf.u[i] = pack2bf(st[tt][8 * s + 2 * i], st[tt][8 * s + 2 * i + 1]);
        const int ks2 = tt * 2 + s;
        __builtin_amdgcn_s_setprio(1);
#pragma unroll
        for (int dt = 0; dt < 2; ++dt) {
          const int drow = dt * 32 + l31;
          bf16x8 vf = *(const bf16x8*)(sV + drow * 64 +
                                       (((ks2 * 2 + h) ^ (drow & 7)) << 3));
          o[dt] = __builtin_amdgcn_mfma_f32_32x32x16_bf16(vf, pf.v, o[dt], 0, 0, 0);
        }
        __builtin_amdgcn_s_setprio(0);
      }
    }

    __syncthreads();   // all waves done reading sV (and sK[cur])
    if (kv < 15) {     // issue-late V stage into the single buffer
      const int kn = kv + 1;
#pragma unroll
      for (int i = 0; i < 2; ++i) {
        int c = i * 256 + t, row = c >> 3, slot = c & 7;
        gload16(Vtg + (size_t)row * 1024 + kn * 64 + ((slot ^ (row & 7)) << 3),
                sV + c * 8);
      }
    }
  }

  // epilogue: two passes (d-halves) through Lbuf[32][129] -> coalesced stores
  const float linv = 1.f / lrow;
#pragma unroll
  for (int half = 0; half < 2; ++half) {
    __syncthreads();
#pragma unroll
    for (int r = 0; r < 16; ++r) {
      const int dloc = (r & 3) + 8 * (r >> 2) + 4 * h;   // 0..31
      Lbuf[dloc * 129 + wave * 32 + l31] = o[half][r] * linv;
    }
    __syncthreads();
    const int qloc = t >> 1, ds0 = (t & 1) * 16;
    float* ob = Out + (size_t)bh * 65536 + (size_t)(qb * 128 + qloc) * 64
              + half * 32 + ds0;
#pragma unroll
    for (int c = 0; c < 4; ++c) {
      float4 v = { Lbuf[(ds0 + 4 * c + 0) * 129 + qloc],
                   Lbuf[(ds0 + 4 * c + 1) * 129 + qloc],
                   Lbuf[(ds0 + 4 * c + 2) * 129 + qloc],
                   Lbuf[(ds0 + 4 * c + 3) * 129 + qloc] };
      *(float4*)(ob + 4 * c) = v;
    }
  }
}

// ---------------- launch ----------------
extern "C" void kernel_launch(void* const* d_in, const int* in_sizes, int n_in,
                              void* d_out, int out_size, void* d_ws, size_t ws_size,
                              hipStream_t stream) {
  (void)in_sizes; (void)n_in; (void)out_size; (void)ws_size;
  const float* x  = (const float*)d_in[0];
  const float* Wq = (const float*)d_in[1];
  const float* bq = (const float*)d_in[2];
  const float* Wk = (const float*)d_in[3];
  const float* bk = (const float*)d_in[4];
  const float* Wv = (const float*)d_in[5];
  const float* bv = (const float*)d_in[6];

  // ws layout (bytes): Xb/VT[32M] | Wb[1.5M] | QKV[96M]
  // Xb is dead after the GEMM; VT reuses its region.
  ushort* Xb  = (ushort*)d_ws;
  ushort* VT  = (ushort*)d_ws;
  ushort* Wb  = (ushort*)((char*)d_ws + 33554432);
  ushort* QKV = (ushort*)((char*)d_ws + 35127296);
  ushort* Vn  = QKV + 2 * (size_t)M_ROWS * 512;   // natural V plane

  cvt_all_kernel<<<2432, 256, 0, stream>>>(x, Wq, Wk, Wv, Xb, Wb);

  qkv_gemm_kernel<<<256 * 12, 256, 0, stream>>>(Xb, Wb, bq, bk, bv, QKV);

  vtrans_kernel<<<1024, 256, 0, stream>>>(Vn, VT);

  attn_kernel<<<256 * 8, 256, 0, stream>>>(QKV, VT, (float*)d_out);
}

// Round 11
// 236.977 us; speedup vs baseline: 2.2329x; 2.1866x over previous
//
#include <hip/hip_runtime.h>
#include <hip/hip_bf16.h>
#include <stdint.h>

#define AS_G __attribute__((address_space(1)))
#define AS_L __attribute__((address_space(3)))

typedef short bf16x8 __attribute__((ext_vector_type(8)));   // bits of 8 bf16
typedef float f32x4  __attribute__((ext_vector_type(4)));
typedef float f32x16 __attribute__((ext_vector_type(16)));
typedef unsigned int u32x2 __attribute__((ext_vector_type(2)));

// Problem constants (B=32, N=1024, D=512, H=8, DH=64)
constexpr int   M_ROWS = 32768;                    // B*N
constexpr float QSCALE = 0.18033688011112042f;     // log2(e) / sqrt(64)

__device__ __forceinline__ ushort f2bf(float f) {  // hw RTNE f32->bf16
  union { __hip_bfloat16 h; ushort u; } c;
  c.h = __float2bfloat16(f);
  return c.u;
}
__device__ __forceinline__ uint32_t pack2bf(float lo, float hi) {
  union { __hip_bfloat162 b; uint32_t u; } r;
  r.b.x = __float2bfloat16(lo);
  r.b.y = __float2bfloat16(hi);
  return r.u;
}
// permlane32_swap(x,x): returns {dup_lo(x), dup_hi(x)} as an unordered set —
// used ONLY in symmetric reductions (fmax / +), correct under either
// dst/src row-order convention.
__device__ __forceinline__ u32x2 pswap(uint32_t x) {
  return __builtin_amdgcn_permlane32_swap(x, x, false, false);
}
__device__ __forceinline__ void gload16(const ushort* g, ushort* l) {
  // async global->LDS, 16B/lane; LDS dest must be uniform_base + lane*16
  __builtin_amdgcn_global_load_lds((const AS_G uint32_t*)g, (AS_L uint32_t*)l, 16, 0, 0);
}

// ---------------- f32 -> bf16 convert (x + 3 W in one launch) ----------------
__device__ __forceinline__ void cvt8(const float* __restrict__ in,
                                     ushort* __restrict__ out, int i) {
  float4 a = reinterpret_cast<const float4*>(in)[2 * i];
  float4 b = reinterpret_cast<const float4*>(in)[2 * i + 1];
  ushort4 o0 = {f2bf(a.x), f2bf(a.y), f2bf(a.z), f2bf(a.w)};
  ushort4 o1 = {f2bf(b.x), f2bf(b.y), f2bf(b.z), f2bf(b.w)};
  reinterpret_cast<ushort4*>(out)[2 * i]     = o0;
  reinterpret_cast<ushort4*>(out)[2 * i + 1] = o1;
}

__global__ __launch_bounds__(256) void cvt_all_kernel(
    const float* __restrict__ x,  const float* __restrict__ wq,
    const float* __restrict__ wk, const float* __restrict__ wv,
    ushort* __restrict__ xb, ushort* __restrict__ wb) {
  const int b = blockIdx.x, t = threadIdx.x;
  if (b < 2048) {                 // x: 2,097,152 groups = 2048*256*4
    const int i0 = b * 256 + t;
#pragma unroll
    for (int rep = 0; rep < 4; ++rep) cvt8(x, xb, i0 + rep * 524288);
  } else {                        // W: 3 mats x 32768 groups (128 blocks each)
    const int c = b - 2048, m = c >> 7;
    const float* src = (m == 0) ? wq : (m == 1 ? wk : wv);
    cvt8(src, wb + m * 262144, (c & 127) * 256 + t);
  }
}

// ---------------- QKV projection GEMM (known-good) ----------------
// C = X @ W^T + bias -> bf16 plane [32768][512]; Q pre-scaled by QSCALE.
__global__ __launch_bounds__(256) void qkv_gemm_kernel(
    const ushort* __restrict__ Xb, const ushort* __restrict__ Wall,
    const float* __restrict__ bq, const float* __restrict__ bk,
    const float* __restrict__ bv,
    ushort* __restrict__ QKV)
{
  __shared__ ushort As[128 * 64];
  __shared__ ushort Bs[128 * 64];

  const int tile = blockIdx.x;
  const int mt  = tile & 255;
  const int cz  = tile >> 8;     // 0..11
  const int mat = cz >> 2;       // 0:q 1:k 2:v
  const int nt  = cz & 3;

  const ushort* W    = Wall + (size_t)mat * (512 * 512);
  const float*  bias = (mat == 0) ? bq : (mat == 1 ? bk : bv);
  ushort*       Out  = QKV + (size_t)mat * ((size_t)M_ROWS * 512);
  const float   oscale = (mat == 0) ? QSCALE : 1.0f;

  const int m0 = mt * 128, n0 = nt * 128;
  const int t = threadIdx.x, lane = t & 63, wave = t >> 6;
  const int wr = wave >> 1, wc = wave & 1;
  const int l15 = lane & 15, lg = lane >> 4;

  f32x4 acc[4][4];
#pragma unroll
  for (int i = 0; i < 4; i++)
#pragma unroll
    for (int j = 0; j < 4; j++) acc[i][j] = {0.f, 0.f, 0.f, 0.f};

  for (int kt = 0; kt < 8; ++kt) {
    const int k0 = kt * 64;
    __syncthreads();
#pragma unroll
    for (int i = 0; i < 4; ++i) {
      int c = i * 256 + t, row = c >> 3, col8 = (c & 7) * 8;
      gload16(Xb + (size_t)(m0 + row) * 512 + k0 + col8, As + c * 8);
    }
#pragma unroll
    for (int i = 0; i < 4; ++i) {
      int c = i * 256 + t, row = c >> 3, col8 = (c & 7) * 8;
      gload16(W + (size_t)(n0 + row) * 512 + k0 + col8, Bs + c * 8);
    }
    __syncthreads();
#pragma unroll
    for (int ks = 0; ks < 2; ++ks) {
      bf16x8 af[4], bfr[4];
#pragma unroll
      for (int i = 0; i < 4; ++i) {
        af[i]  = *(const bf16x8*)(As + (wr * 64 + i * 16 + l15) * 64 + ks * 32 + lg * 8);
        bfr[i] = *(const bf16x8*)(Bs + (wc * 64 + i * 16 + l15) * 64 + ks * 32 + lg * 8);
      }
#pragma unroll
      for (int i = 0; i < 4; ++i)
#pragma unroll
        for (int j = 0; j < 4; ++j)
          acc[i][j] = __builtin_amdgcn_mfma_f32_16x16x32_bf16(af[i], bfr[j], acc[i][j], 0, 0, 0);
    }
  }
#pragma unroll
  for (int j = 0; j < 4; ++j) {
    const int col = n0 + wc * 64 + j * 16 + l15;
    const float bc = bias[col];
#pragma unroll
    for (int i = 0; i < 4; ++i) {
      const int row0 = m0 + wr * 64 + i * 16 + lg * 4;
#pragma unroll
      for (int r = 0; r < 4; ++r)
        Out[(size_t)(row0 + r) * 512 + col] = f2bf((acc[i][j][r] + bc) * oscale);
    }
  }
}

// ---------------- V transpose + key permutation --------------------------
// VT'[bh][dh][n64*64 + p] = flatV[bh*65536 + (n64*64 + pi(p))*64 + dh]
// pi(p): with p = tt*32 + s*16 + h*8 + j  ->  tt*32 + 16s + 4h + (j&3) + 8*(j>>2).
// This matches the MFMA C-layout crow() of the swapped QK^T, so the attention
// PV B-fragment needs NO cross-lane exchange.
__global__ __launch_bounds__(256) void vtrans_kernel(
    const ushort* __restrict__ Vn, ushort* __restrict__ VT)
{
  __shared__ ushort T[64][258];   // [dh][n-local], padded stride
  const int bh = blockIdx.x >> 2, nc = blockIdx.x & 3;
  const ushort* src = Vn + (size_t)bh * 65536 + nc * 16384;
  ushort* dst = VT + (size_t)bh * 65536 + nc * 256;
  const int t = threadIdx.x;
#pragma unroll
  for (int i = 0; i < 8; ++i) {   // load [256 n][64 dh], scatter-transpose
    int c = i * 256 + t, n = c >> 3, col8 = (c & 7) * 8;
    ushort tmp[8];
    *(int4*)tmp = *(const int4*)(src + n * 64 + col8);
#pragma unroll
    for (int j = 0; j < 8; ++j) T[col8 + j][n] = tmp[j];
  }
  __syncthreads();
#pragma unroll
  for (int i = 0; i < 8; ++i) {   // write [64 dh][256 n] coalesced, pi-gathered
    int c = i * 256 + t, dh = c >> 5, a8 = (c & 31) * 8;
    const int w = a8 & 63;        // position of this 8-group within its 64-tile
    const int pbase = (a8 & 192) + (w >> 5) * 32 + ((w >> 4) & 1) * 16
                    + ((w >> 3) & 1) * 4;
    ushort tmp[8];
    *(uint64_t*)(tmp)     = *(const uint64_t*)(&T[dh][pbase]);      // j=0..3
    *(uint64_t*)(tmp + 4) = *(const uint64_t*)(&T[dh][pbase + 8]);  // j=4..7
    *(int4*)(dst + (size_t)dh * 1024 + a8) = *(const int4*)tmp;
  }
}

// ---------------- flash attention: 4 waves x 32 q-rows, KVBLK=64, 32x32x16 ----
// Swapped QK^T (S^T = K Q^T) -> lane-local softmax; V key-permuted so the PV
// B-fragment is the lane's own packed P values (no cross-lane exchange).
// K double-buffered (issue-early); V SINGLE-buffered (issue-late). 24 KB LDS
// -> 6 blocks/CU. launch_bounds(256,4): (256,6) forced VGPR 40 -> scratch
// spill (round 10: FETCH 748 MB / WRITE 921 MB of spill traffic). At ~60
// VGPR the register file still allows 8 waves/SIMD, so LDS is the binding
// limit and occupancy reaches 6 blocks/CU without spilling.
__global__ __launch_bounds__(256, 4) void attn_kernel(
    const ushort* __restrict__ QKV,   // planes: Q[bh][n][64], K[bh][n][64]
    const ushort* __restrict__ VTg_,  // V^T [bh][64 dh][1024 n], key-permuted
    float* __restrict__ Out)          // [bh][1024][64] f32
{
  constexpr int PLANE = M_ROWS * 512;
  __shared__ ushort SMEM[12288];              // 24576 B: sK[2][4096] | sV[4096]
  ushort* sK = SMEM;
  ushort* sV = SMEM + 8192;
  float* Lbuf = (float*)SMEM;                 // epilogue alias [32][129]=16512 B

  const int raw = blockIdx.x;                 // 2048 = 8 XCD chunks x 256
  const int blk = ((raw & 7) << 8) | (raw >> 3);
  const int bh = blk >> 3, qb = blk & 7;
  const ushort* Qg  = QKV + (size_t)bh * 65536;
  const ushort* Kg  = QKV + (size_t)PLANE + (size_t)bh * 65536;
  const ushort* Vtg = VTg_ + (size_t)bh * 65536;

  const int t = threadIdx.x, lane = t & 63, wave = t >> 6;
  const int l31 = lane & 31, h = lane >> 5;
  const int q = qb * 128 + wave * 32 + l31;

  bf16x8 qf[4];
#pragma unroll
  for (int ks = 0; ks < 4; ++ks)
    qf[ks] = *(const bf16x8*)(Qg + (size_t)q * 64 + ks * 16 + h * 8);

  float mrow = -1e30f, lrow = 0.f;
  f32x16 o[2];
#pragma unroll
  for (int r = 0; r < 16; ++r) { o[0][r] = 0.f; o[1][r] = 0.f; }

  // prologue: issue K0 -> sK[0], V0 -> sV (drained at first in-loop barrier)
#pragma unroll
  for (int i = 0; i < 2; ++i) {
    int c = i * 256 + t, row = c >> 3, slot = c & 7;
    gload16(Kg + (size_t)row * 64 + ((slot ^ (row & 7)) << 3), sK + c * 8);
    gload16(Vtg + (size_t)row * 1024 + ((slot ^ (row & 7)) << 3), sV + c * 8);
  }

  for (int kv = 0; kv < 16; ++kv) {
    const int cur = kv & 1;
    __syncthreads();   // drains vmcnt: K[kv] + V[kv] landed; prior reads done
    if (kv < 15) {     // issue-early K prefetch (overlaps this iter's compute)
      const int kn = kv + 1;
#pragma unroll
      for (int i = 0; i < 2; ++i) {
        int c = i * 256 + t, row = c >> 3, slot = c & 7;
        gload16(Kg + (size_t)(kn * 64 + row) * 64 + ((slot ^ (row & 7)) << 3),
                sK + (cur ^ 1) * 4096 + c * 8);
      }
    }
    const ushort* Kc = sK + cur * 4096;

    // S^T = K Q^T : lane holds S[k = tt*32 + (r&3)+8*(r>>2)+4h][q = l31]
    f32x16 st[2];
#pragma unroll
    for (int tt = 0; tt < 2; ++tt) {
      f32x16 a;
#pragma unroll
      for (int r = 0; r < 16; ++r) a[r] = 0.f;
      __builtin_amdgcn_s_setprio(1);
#pragma unroll
      for (int ks = 0; ks < 4; ++ks) {
        const int krow = tt * 32 + l31;
        bf16x8 kf = *(const bf16x8*)(Kc + krow * 64 + (((ks * 2 + h) ^ (krow & 7)) << 3));
        a = __builtin_amdgcn_mfma_f32_32x32x16_bf16(kf, qf[ks], a, 0, 0, 0);
      }
      __builtin_amdgcn_s_setprio(0);
      st[tt] = a;
    }

    // online softmax (row = q = l31): tree max, cross-half via permlane (symmetric)
    float mx;
    {
      float t8[8];
#pragma unroll
      for (int i = 0; i < 8; ++i)
        t8[i] = fmaxf(fmaxf(st[0][i], st[0][i + 8]), fmaxf(st[1][i], st[1][i + 8]));
      float a0 = fmaxf(fmaxf(t8[0], t8[1]), fmaxf(t8[2], t8[3]));
      float a1 = fmaxf(fmaxf(t8[4], t8[5]), fmaxf(t8[6], t8[7]));
      mx = fmaxf(a0, a1);
    }
    {
      u32x2 d = pswap(__float_as_uint(mx));
      mx = fmaxf(__uint_as_float(d.x), __uint_as_float(d.y));
    }
    if (!__all(mx - mrow <= 8.0f)) {       // defer-max: rescale rare after t0
      const float mnew = fmaxf(mrow, mx);
      const float alpha = exp2f(mrow - mnew);
      mrow = mnew;
      lrow *= alpha;
#pragma unroll
      for (int r = 0; r < 16; ++r) { o[0][r] *= alpha; o[1][r] *= alpha; }
    }
#pragma unroll
    for (int tt = 0; tt < 2; ++tt)
#pragma unroll
      for (int r = 0; r < 16; ++r) st[tt][r] = exp2f(st[tt][r] - mrow);
    {
      float s8[8];
#pragma unroll
      for (int i = 0; i < 8; ++i)
        s8[i] = (st[0][i] + st[0][i + 8]) + (st[1][i] + st[1][i + 8]);
      float rs = ((s8[0] + s8[1]) + (s8[2] + s8[3]))
               + ((s8[4] + s8[5]) + (s8[6] + s8[7]));
      u32x2 d = pswap(__float_as_uint(rs));
      lrow += __uint_as_float(d.x) + __uint_as_float(d.y);
    }

    // O^T += V'^T P'^T : V key-permuted so pf = own packed st values.
#pragma unroll
    for (int tt = 0; tt < 2; ++tt) {
#pragma unroll
      for (int s = 0; s < 2; ++s) {
        union { uint32_t u[4]; bf16x8 v; } pf;
#pragma unroll
        for (int i = 0; i < 4; ++i)
          pf.u[i] = pack2bf(st[tt][8 * s + 2 * i], st[tt][8 * s + 2 * i + 1]);
        const int ks2 = tt * 2 + s;
        __builtin_amdgcn_s_setprio(1);
#pragma unroll
        for (int dt = 0; dt < 2; ++dt) {
          const int drow = dt * 32 + l31;
          bf16x8 vf = *(const bf16x8*)(sV + drow * 64 +
                                       (((ks2 * 2 + h) ^ (drow & 7)) << 3));
          o[dt] = __builtin_amdgcn_mfma_f32_32x32x16_bf16(vf, pf.v, o[dt], 0, 0, 0);
        }
        __builtin_amdgcn_s_setprio(0);
      }
    }

    __syncthreads();   // all waves done reading sV (and sK[cur])
    if (kv < 15) {     // issue-late V stage into the single buffer
      const int kn = kv + 1;
#pragma unroll
      for (int i = 0; i < 2; ++i) {
        int c = i * 256 + t, row = c >> 3, slot = c & 7;
        gload16(Vtg + (size_t)row * 1024 + kn * 64 + ((slot ^ (row & 7)) << 3),
                sV + c * 8);
      }
    }
  }

  // epilogue: two passes (d-halves) through Lbuf[32][129] -> coalesced stores
  const float linv = 1.f / lrow;
#pragma unroll
  for (int half = 0; half < 2; ++half) {
    __syncthreads();
#pragma unroll
    for (int r = 0; r < 16; ++r) {
      const int dloc = (r & 3) + 8 * (r >> 2) + 4 * h;   // 0..31
      Lbuf[dloc * 129 + wave * 32 + l31] = o[half][r] * linv;
    }
    __syncthreads();
    const int qloc = t >> 1, ds0 = (t & 1) * 16;
    float* ob = Out + (size_t)bh * 65536 + (size_t)(qb * 128 + qloc) * 64
              + half * 32 + ds0;
#pragma unroll
    for (int c = 0; c < 4; ++c) {
      float4 v = { Lbuf[(ds0 + 4 * c + 0) * 129 + qloc],
                   Lbuf[(ds0 + 4 * c + 1) * 129 + qloc],
                   Lbuf[(ds0 + 4 * c + 2) * 129 + qloc],
                   Lbuf[(ds0 + 4 * c + 3) * 129 + qloc] };
      *(float4*)(ob + 4 * c) = v;
    }
  }
}

// ---------------- launch ----------------
extern "C" void kernel_launch(void* const* d_in, const int* in_sizes, int n_in,
                              void* d_out, int out_size, void* d_ws, size_t ws_size,
                              hipStream_t stream) {
  (void)in_sizes; (void)n_in; (void)out_size; (void)ws_size;
  const float* x  = (const float*)d_in[0];
  const float* Wq = (const float*)d_in[1];
  const float* bq = (const float*)d_in[2];
  const float* Wk = (const float*)d_in[3];
  const float* bk = (const float*)d_in[4];
  const float* Wv = (const float*)d_in[5];
  const float* bv = (const float*)d_in[6];

  // ws layout (bytes): Xb/VT[32M] | Wb[1.5M] | QKV[96M]
  // Xb is dead after the GEMM; VT reuses its region.
  ushort* Xb  = (ushort*)d_ws;
  ushort* VT  = (ushort*)d_ws;
  ushort* Wb  = (ushort*)((char*)d_ws + 33554432);
  ushort* QKV = (ushort*)((char*)d_ws + 35127296);
  ushort* Vn  = QKV + 2 * (size_t)M_ROWS * 512;   // natural V plane

  cvt_all_kernel<<<2432, 256, 0, stream>>>(x, Wq, Wk, Wv, Xb, Wb);

  qkv_gemm_kernel<<<256 * 12, 256, 0, stream>>>(Xb, Wb, bq, bk, bv, QKV);

  vtrans_kernel<<<1024, 256, 0, stream>>>(Vn, VT);

  attn_kernel<<<256 * 8, 256, 0, stream>>>(QKV, VT, (float*)d_out);
}

// Round 12
// 235.612 us; speedup vs baseline: 2.2458x; 1.0058x over previous
//
#include <hip/hip_runtime.h>
#include <hip/hip_bf16.h>
#include <stdint.h>

#define AS_G __attribute__((address_space(1)))
#define AS_L __attribute__((address_space(3)))

typedef short bf16x8 __attribute__((ext_vector_type(8)));   // bits of 8 bf16
typedef float f32x4  __attribute__((ext_vector_type(4)));
typedef float f32x16 __attribute__((ext_vector_type(16)));
typedef unsigned int u32x2 __attribute__((ext_vector_type(2)));

// Problem constants (B=32, N=1024, D=512, H=8, DH=64)
constexpr int   M_ROWS = 32768;                    // B*N
constexpr float QSCALE = 0.18033688011112042f;     // log2(e) / sqrt(64)

__device__ __forceinline__ ushort f2bf(float f) {  // hw RTNE f32->bf16
  union { __hip_bfloat16 h; ushort u; } c;
  c.h = __float2bfloat16(f);
  return c.u;
}
__device__ __forceinline__ uint32_t pack2bf(float lo, float hi) {
  union { __hip_bfloat162 b; uint32_t u; } r;
  r.b.x = __float2bfloat16(lo);
  r.b.y = __float2bfloat16(hi);
  return r.u;
}
// permlane32_swap(x,x): returns {dup_lo(x), dup_hi(x)} as an unordered set —
// used ONLY in symmetric reductions (fmax / +), correct under either
// dst/src row-order convention.
__device__ __forceinline__ u32x2 pswap(uint32_t x) {
  return __builtin_amdgcn_permlane32_swap(x, x, false, false);
}
__device__ __forceinline__ void gload16(const ushort* g, ushort* l) {
  // async global->LDS, 16B/lane; LDS dest must be uniform_base + lane*16
  __builtin_amdgcn_global_load_lds((const AS_G uint32_t*)g, (AS_L uint32_t*)l, 16, 0, 0);
}

// ---------------- f32 -> bf16 convert (x + 3 W in one launch) ----------------
__device__ __forceinline__ void cvt8(const float* __restrict__ in,
                                     ushort* __restrict__ out, int i) {
  float4 a = reinterpret_cast<const float4*>(in)[2 * i];
  float4 b = reinterpret_cast<const float4*>(in)[2 * i + 1];
  ushort4 o0 = {f2bf(a.x), f2bf(a.y), f2bf(a.z), f2bf(a.w)};
  ushort4 o1 = {f2bf(b.x), f2bf(b.y), f2bf(b.z), f2bf(b.w)};
  reinterpret_cast<ushort4*>(out)[2 * i]     = o0;
  reinterpret_cast<ushort4*>(out)[2 * i + 1] = o1;
}

__global__ __launch_bounds__(256) void cvt_all_kernel(
    const float* __restrict__ x,  const float* __restrict__ wq,
    const float* __restrict__ wk, const float* __restrict__ wv,
    ushort* __restrict__ xb, ushort* __restrict__ wb) {
  const int b = blockIdx.x, t = threadIdx.x;
  if (b < 2048) {                 // x: 2,097,152 groups = 2048*256*4
    const int i0 = b * 256 + t;
#pragma unroll
    for (int rep = 0; rep < 4; ++rep) cvt8(x, xb, i0 + rep * 524288);
  } else {                        // W: 3 mats x 32768 groups (128 blocks each)
    const int c = b - 2048, m = c >> 7;
    const float* src = (m == 0) ? wq : (m == 1 ? wk : wv);
    cvt8(src, wb + m * 262144, (c & 127) * 256 + t);
  }
}

// ---------------- QKV projection GEMM (known-good) ----------------
// C = X @ W^T + bias -> bf16 plane [32768][512]; Q pre-scaled by QSCALE.
__global__ __launch_bounds__(256) void qkv_gemm_kernel(
    const ushort* __restrict__ Xb, const ushort* __restrict__ Wall,
    const float* __restrict__ bq, const float* __restrict__ bk,
    const float* __restrict__ bv,
    ushort* __restrict__ QKV)
{
  __shared__ ushort As[128 * 64];
  __shared__ ushort Bs[128 * 64];

  const int tile = blockIdx.x;
  const int mt  = tile & 255;
  const int cz  = tile >> 8;     // 0..11
  const int mat = cz >> 2;       // 0:q 1:k 2:v
  const int nt  = cz & 3;

  const ushort* W    = Wall + (size_t)mat * (512 * 512);
  const float*  bias = (mat == 0) ? bq : (mat == 1 ? bk : bv);
  ushort*       Out  = QKV + (size_t)mat * ((size_t)M_ROWS * 512);
  const float   oscale = (mat == 0) ? QSCALE : 1.0f;

  const int m0 = mt * 128, n0 = nt * 128;
  const int t = threadIdx.x, lane = t & 63, wave = t >> 6;
  const int wr = wave >> 1, wc = wave & 1;
  const int l15 = lane & 15, lg = lane >> 4;

  f32x4 acc[4][4];
#pragma unroll
  for (int i = 0; i < 4; i++)
#pragma unroll
    for (int j = 0; j < 4; j++) acc[i][j] = {0.f, 0.f, 0.f, 0.f};

  for (int kt = 0; kt < 8; ++kt) {
    const int k0 = kt * 64;
    __syncthreads();
#pragma unroll
    for (int i = 0; i < 4; ++i) {
      int c = i * 256 + t, row = c >> 3, col8 = (c & 7) * 8;
      gload16(Xb + (size_t)(m0 + row) * 512 + k0 + col8, As + c * 8);
    }
#pragma unroll
    for (int i = 0; i < 4; ++i) {
      int c = i * 256 + t, row = c >> 3, col8 = (c & 7) * 8;
      gload16(W + (size_t)(n0 + row) * 512 + k0 + col8, Bs + c * 8);
    }
    __syncthreads();
#pragma unroll
    for (int ks = 0; ks < 2; ++ks) {
      bf16x8 af[4], bfr[4];
#pragma unroll
      for (int i = 0; i < 4; ++i) {
        af[i]  = *(const bf16x8*)(As + (wr * 64 + i * 16 + l15) * 64 + ks * 32 + lg * 8);
        bfr[i] = *(const bf16x8*)(Bs + (wc * 64 + i * 16 + l15) * 64 + ks * 32 + lg * 8);
      }
#pragma unroll
      for (int i = 0; i < 4; ++i)
#pragma unroll
        for (int j = 0; j < 4; ++j)
          acc[i][j] = __builtin_amdgcn_mfma_f32_16x16x32_bf16(af[i], bfr[j], acc[i][j], 0, 0, 0);
    }
  }
#pragma unroll
  for (int j = 0; j < 4; ++j) {
    const int col = n0 + wc * 64 + j * 16 + l15;
    const float bc = bias[col];
#pragma unroll
    for (int i = 0; i < 4; ++i) {
      const int row0 = m0 + wr * 64 + i * 16 + lg * 4;
#pragma unroll
      for (int r = 0; r < 4; ++r)
        Out[(size_t)(row0 + r) * 512 + col] = f2bf((acc[i][j][r] + bc) * oscale);
    }
  }
}

// ---------------- V transpose + key permutation --------------------------
// VT'[bh][dh][n64*64 + p] = flatV[bh*65536 + (n64*64 + pi(p))*64 + dh]
// pi(p): with p = tt*32 + s*16 + h*8 + j  ->  tt*32 + 16s + 4h + (j&3) + 8*(j>>2).
// This matches the MFMA C-layout crow() of the swapped QK^T, so the attention
// PV B-fragment needs NO cross-lane exchange.
__global__ __launch_bounds__(256) void vtrans_kernel(
    const ushort* __restrict__ Vn, ushort* __restrict__ VT)
{
  __shared__ ushort T[64][258];   // [dh][n-local], padded stride
  const int bh = blockIdx.x >> 2, nc = blockIdx.x & 3;
  const ushort* src = Vn + (size_t)bh * 65536 + nc * 16384;
  ushort* dst = VT + (size_t)bh * 65536 + nc * 256;
  const int t = threadIdx.x;
#pragma unroll
  for (int i = 0; i < 8; ++i) {   // load [256 n][64 dh], scatter-transpose
    int c = i * 256 + t, n = c >> 3, col8 = (c & 7) * 8;
    ushort tmp[8];
    *(int4*)tmp = *(const int4*)(src + n * 64 + col8);
#pragma unroll
    for (int j = 0; j < 8; ++j) T[col8 + j][n] = tmp[j];
  }
  __syncthreads();
#pragma unroll
  for (int i = 0; i < 8; ++i) {   // write [64 dh][256 n] coalesced, pi-gathered
    int c = i * 256 + t, dh = c >> 5, a8 = (c & 31) * 8;
    const int w = a8 & 63;        // position of this 8-group within its 64-tile
    const int pbase = (a8 & 192) + (w >> 5) * 32 + ((w >> 4) & 1) * 16
                    + ((w >> 3) & 1) * 4;
    ushort tmp[8];
    *(uint64_t*)(tmp)     = *(const uint64_t*)(&T[dh][pbase]);      // j=0..3
    *(uint64_t*)(tmp + 4) = *(const uint64_t*)(&T[dh][pbase + 8]);  // j=4..7
    *(int4*)(dst + (size_t)dh * 1024 + a8) = *(const int4*)tmp;
  }
}

// ---------------- flash attention: 4 waves x 32 q-rows, KVBLK=128, 32x32x16 ---
// Swapped QK^T (S^T = K Q^T) -> lane-local softmax; V key-permuted so the PV
// B-fragment is the lane's own packed P values. KVBLK=128 doubles per-phase
// independent MFMA chains (4 QK^T accs, 8 PV slices) and halves barrier
// events (8 iters) — attacks the serial-chain latency that r7/r11 pinned at
// ~136 us. K double-buffered (issue-early); V single-buffered (issue-late).
// LDS 48 KB -> 3 blocks/CU (the residency we measure anyway).
__global__ __launch_bounds__(256, 3) void attn_kernel(
    const ushort* __restrict__ QKV,   // planes: Q[bh][n][64], K[bh][n][64]
    const ushort* __restrict__ VTg_,  // V^T [bh][64 dh][1024 n], key-permuted
    float* __restrict__ Out)          // [bh][1024][64] f32
{
  constexpr int PLANE = M_ROWS * 512;
  __shared__ ushort SMEM[24576];   // 49152 B: sK[2][8192] | sV[8192]
  ushort* sK = SMEM;               // K tile [128 rows][64], 16 KB x2
  ushort* sV = SMEM + 16384;       // V tile [64 dh][128 keys], 16 KB
  float* Lbuf = (float*)SMEM;      // epilogue alias [32][129] = 16512 B

  const int raw = blockIdx.x;      // 2048 = 8 XCD chunks x 256
  const int blk = ((raw & 7) << 8) | (raw >> 3);
  const int bh = blk >> 3, qb = blk & 7;
  const ushort* Qg  = QKV + (size_t)bh * 65536;
  const ushort* Kg  = QKV + (size_t)PLANE + (size_t)bh * 65536;
  const ushort* Vtg = VTg_ + (size_t)bh * 65536;

  const int t = threadIdx.x, lane = t & 63, wave = t >> 6;
  const int l31 = lane & 31, h = lane >> 5;
  const int q = qb * 128 + wave * 32 + l31;

  bf16x8 qf[4];
#pragma unroll
  for (int ks = 0; ks < 4; ++ks)
    qf[ks] = *(const bf16x8*)(Qg + (size_t)q * 64 + ks * 16 + h * 8);

  float mrow = -1e30f, lrow = 0.f;
  f32x16 o[2];
#pragma unroll
  for (int r = 0; r < 16; ++r) { o[0][r] = 0.f; o[1][r] = 0.f; }

  // prologue: issue K0 -> sK[0] (4x) and V0 -> sV (4x)
#pragma unroll
  for (int i = 0; i < 4; ++i) {
    int c = i * 256 + t;
    int krow = c >> 3, kslot = c & 7;
    gload16(Kg + (size_t)krow * 64 + ((kslot ^ (krow & 7)) << 3), sK + c * 8);
    int vrow = c >> 4, vslot = c & 15;
    gload16(Vtg + (size_t)vrow * 1024 + ((vslot ^ (vrow & 15)) << 3), sV + c * 8);
  }

  for (int kv = 0; kv < 8; ++kv) {
    const int cur = kv & 1;
    __syncthreads();   // drains vmcnt: K[kv] + V[kv] landed; prior reads done
    if (kv < 7) {      // issue-early K prefetch (overlaps this iter's compute)
      const int kn = kv + 1;
#pragma unroll
      for (int i = 0; i < 4; ++i) {
        int c = i * 256 + t, row = c >> 3, slot = c & 7;
        gload16(Kg + (size_t)(kn * 128 + row) * 64 + ((slot ^ (row & 7)) << 3),
                sK + (cur ^ 1) * 8192 + c * 8);
      }
    }
    const ushort* Kc = sK + cur * 8192;

    // S^T = K Q^T : 4 independent accumulators (tt = key-32-group)
    f32x16 st[4];
#pragma unroll
    for (int tt = 0; tt < 4; ++tt) {
      f32x16 a;
#pragma unroll
      for (int r = 0; r < 16; ++r) a[r] = 0.f;
      __builtin_amdgcn_s_setprio(1);
#pragma unroll
      for (int ks = 0; ks < 4; ++ks) {
        const int krow = tt * 32 + l31;
        bf16x8 kf = *(const bf16x8*)(Kc + krow * 64 + (((ks * 2 + h) ^ (krow & 7)) << 3));
        a = __builtin_amdgcn_mfma_f32_32x32x16_bf16(kf, qf[ks], a, 0, 0, 0);
      }
      __builtin_amdgcn_s_setprio(0);
      st[tt] = a;
    }

    // online softmax over 64 values (row = q = l31), cross-half via permlane
    float mx;
    {
      float t8[8];
#pragma unroll
      for (int i = 0; i < 8; ++i) {
        float a0 = fmaxf(fmaxf(st[0][i], st[1][i]), fmaxf(st[2][i], st[3][i]));
        float a1 = fmaxf(fmaxf(st[0][i + 8], st[1][i + 8]),
                         fmaxf(st[2][i + 8], st[3][i + 8]));
        t8[i] = fmaxf(a0, a1);
      }
      float b0 = fmaxf(fmaxf(t8[0], t8[1]), fmaxf(t8[2], t8[3]));
      float b1 = fmaxf(fmaxf(t8[4], t8[5]), fmaxf(t8[6], t8[7]));
      mx = fmaxf(b0, b1);
    }
    {
      u32x2 d = pswap(__float_as_uint(mx));
      mx = fmaxf(__uint_as_float(d.x), __uint_as_float(d.y));
    }
    if (!__all(mx - mrow <= 8.0f)) {       // defer-max: rescale rare after t0
      const float mnew = fmaxf(mrow, mx);
      const float alpha = exp2f(mrow - mnew);
      mrow = mnew;
      lrow *= alpha;
#pragma unroll
      for (int r = 0; r < 16; ++r) { o[0][r] *= alpha; o[1][r] *= alpha; }
    }
#pragma unroll
    for (int tt = 0; tt < 4; ++tt)
#pragma unroll
      for (int r = 0; r < 16; ++r) st[tt][r] = exp2f(st[tt][r] - mrow);
    {
      float s8[8];
#pragma unroll
      for (int i = 0; i < 8; ++i)
        s8[i] = ((st[0][i] + st[0][i + 8]) + (st[1][i] + st[1][i + 8]))
              + ((st[2][i] + st[2][i + 8]) + (st[3][i] + st[3][i + 8]));
      float rs = ((s8[0] + s8[1]) + (s8[2] + s8[3]))
               + ((s8[4] + s8[5]) + (s8[6] + s8[7]));
      u32x2 d = pswap(__float_as_uint(rs));
      lrow += __uint_as_float(d.x) + __uint_as_float(d.y);
    }

    // O^T += V'^T P'^T : 8 K=16 slices, pf = own packed st values.
#pragma unroll
    for (int ks2 = 0; ks2 < 8; ++ks2) {
      const int tt = ks2 >> 1, s = ks2 & 1;
      union { uint32_t u[4]; bf16x8 v; } pf;
#pragma unroll
      for (int i = 0; i < 4; ++i)
        pf.u[i] = pack2bf(st[tt][8 * s + 2 * i], st[tt][8 * s + 2 * i + 1]);
      __builtin_amdgcn_s_setprio(1);
#pragma unroll
      for (int dt = 0; dt < 2; ++dt) {
        const int drow = dt * 32 + l31;
        bf16x8 vf = *(const bf16x8*)(sV + drow * 128 +
                                     (((ks2 * 2 + h) ^ (drow & 15)) << 3));
        o[dt] = __builtin_amdgcn_mfma_f32_32x32x16_bf16(vf, pf.v, o[dt], 0, 0, 0);
      }
      __builtin_amdgcn_s_setprio(0);
    }

    __syncthreads();   // all waves done reading sV (and sK[cur])
    if (kv < 7) {      // issue-late V stage into the single buffer
      const int kn = kv + 1;
#pragma unroll
      for (int i = 0; i < 4; ++i) {
        int c = i * 256 + t, row = c >> 4, slot = c & 15;
        gload16(Vtg + (size_t)row * 1024 + kn * 128 + ((slot ^ (row & 15)) << 3),
                sV + c * 8);
      }
    }
  }

  // epilogue: two passes (d-halves) through Lbuf[32][129] -> coalesced stores
  const float linv = 1.f / lrow;
#pragma unroll
  for (int half = 0; half < 2; ++half) {
    __syncthreads();
#pragma unroll
    for (int r = 0; r < 16; ++r) {
      const int dloc = (r & 3) + 8 * (r >> 2) + 4 * h;   // 0..31
      Lbuf[dloc * 129 + wave * 32 + l31] = o[half][r] * linv;
    }
    __syncthreads();
    const int qloc = t >> 1, ds0 = (t & 1) * 16;
    float* ob = Out + (size_t)bh * 65536 + (size_t)(qb * 128 + qloc) * 64
              + half * 32 + ds0;
#pragma unroll
    for (int c = 0; c < 4; ++c) {
      float4 v = { Lbuf[(ds0 + 4 * c + 0) * 129 + qloc],
                   Lbuf[(ds0 + 4 * c + 1) * 129 + qloc],
                   Lbuf[(ds0 + 4 * c + 2) * 129 + qloc],
                   Lbuf[(ds0 + 4 * c + 3) * 129 + qloc] };
      *(float4*)(ob + 4 * c) = v;
    }
  }
}

// ---------------- launch ----------------
extern "C" void kernel_launch(void* const* d_in, const int* in_sizes, int n_in,
                              void* d_out, int out_size, void* d_ws, size_t ws_size,
                              hipStream_t stream) {
  (void)in_sizes; (void)n_in; (void)out_size; (void)ws_size;
  const float* x  = (const float*)d_in[0];
  const float* Wq = (const float*)d_in[1];
  const float* bq = (const float*)d_in[2];
  const float* Wk = (const float*)d_in[3];
  const float* bk = (const float*)d_in[4];
  const float* Wv = (const float*)d_in[5];
  const float* bv = (const float*)d_in[6];

  // ws layout (bytes): Xb/VT[32M] | Wb[1.5M] | QKV[96M]
  // Xb is dead after the GEMM; VT reuses its region.
  ushort* Xb  = (ushort*)d_ws;
  ushort* VT  = (ushort*)d_ws;
  ushort* Wb  = (ushort*)((char*)d_ws + 33554432);
  ushort* QKV = (ushort*)((char*)d_ws + 35127296);
  ushort* Vn  = QKV + 2 * (size_t)M_ROWS * 512;   // natural V plane

  cvt_all_kernel<<<2432, 256, 0, stream>>>(x, Wq, Wk, Wv, Xb, Wb);

  qkv_gemm_kernel<<<256 * 12, 256, 0, stream>>>(Xb, Wb, bq, bk, bv, QKV);

  vtrans_kernel<<<1024, 256, 0, stream>>>(Vn, VT);

  attn_kernel<<<256 * 8, 256, 0, stream>>>(QKV, VT, (float*)d_out);
}